// Round 8
// baseline (805.438 us; speedup 1.0000x reference)
//
#include <hip/hip_runtime.h>
#include <math.h>

#define BB 16
#define SS 64
#define NN 128
#define FF 16
#define HH 64
#define EE 1024
#define ET 1152   // EE + NN self-loops
#define XPAD 65   // 65 % 32 == 1: conflict-free column gather (measured 0 conflicts)

typedef float v2f __attribute__((ext_vector_type(2)));

__device__ __forceinline__ float readlane_f(float v, int k) {
  return __int_as_float(__builtin_amdgcn_readlane(__float_as_int(v), k));
}
__device__ __forceinline__ float sigmoidf_(float x) { return 1.f / (1.f + expf(-x)); }
__device__ __forceinline__ float sum4(float4 a) { return (a.x + a.y) + (a.z + a.w); }

// ---------------- CSR + padded-edge-list setup -------------------------------
// Also emits a per-node PADDED edge list (uniform stride PL = max-degree
// rounded to 8): entry = edge_idx<<7 | src; pads = ET<<7 (p_hst[ET] == 0).
__global__ void setup_csr_kernel(const int* __restrict__ ei,
                                 int* __restrict__ csrc,
                                 int* __restrict__ ctgt,
                                 int* __restrict__ plv,
                                 int* __restrict__ pad) {
  __shared__ int deg[NN], cur[NN], offs[NN + 1];
  __shared__ int PLs;
  int tid = threadIdx.x;
  if (tid < NN) deg[tid] = 0;
  __syncthreads();
  for (int e = tid; e < ET; e += 256) {
    int tg = (e < EE) ? ei[EE + e] : (e - EE);
    atomicAdd(&deg[tg], 1);
  }
  __syncthreads();
  if (tid == 0) {
    int s = 0;
    for (int i = 0; i < NN; ++i) { offs[i] = s; s += deg[i]; }
    offs[NN] = s;
    int m = 0;
    for (int i = 0; i < NN; ++i) m = max(m, deg[i]);
    m = (m + 7) & ~7;
    PLs = m;
    plv[0] = m;
  }
  __syncthreads();
  if (tid < NN) cur[tid] = offs[tid];
  __syncthreads();
  for (int e = tid; e < ET; e += 256) {
    int sv, tg;
    if (e < EE) { sv = ei[e]; tg = ei[EE + e]; }
    else        { sv = e - EE; tg = e - EE; }
    int pos = atomicAdd(&cur[tg], 1);
    csrc[pos] = sv;
    ctgt[pos] = tg;
  }
  __syncthreads();          // csrc visible (same CU, waitcnt drained)
  int PL = PLs;
  for (int idx = tid; idx < NN * PL; idx += 256) {
    int n2 = idx / PL, u = idx - n2 * PL;
    int o0 = offs[n2], dg = offs[n2 + 1] - o0;
    int e = o0 + u;
    pad[idx] = (u < dg) ? ((e << 7) | (csrc[e] & 127)) : (ET << 7);
  }
}

// ---------------- input projection: h = x @ W^T + b --------------------------
__global__ __launch_bounds__(256) void input_proj2_kernel(
    const float* __restrict__ x, const float* __restrict__ W,
    const float* __restrict__ bvec, float* __restrict__ h) {
  __shared__ __align__(16) float xs[128 * FF];   // 8 KB
  int tid = threadIdx.x, lane = tid & 63, wid = tid >> 6;
  size_t base = (size_t)blockIdx.x * (128 * FF);
  *(float4*)&xs[tid * 4]        = *(const float4*)(x + base + tid * 4);
  *(float4*)&xs[tid * 4 + 1024] = *(const float4*)(x + base + tid * 4 + 1024);
  float4 w4[FF / 4];
#pragma unroll
  for (int i = 0; i < FF / 4; ++i) w4[i] = ((const float4*)(W + lane * FF))[i];
  float bias = bvec[lane];
  __syncthreads();
  int r0 = wid * 32;
#pragma unroll 4
  for (int r = r0; r < r0 + 32; ++r) {
    const float4* xr = (const float4*)&xs[r * FF];   // LDS broadcast
    float4 a = {bias, 0.f, 0.f, 0.f};
#pragma unroll
    for (int f = 0; f < FF / 4; ++f) a += xr[f] * w4[f];
    h[(size_t)blockIdx.x * (128 * HH) + (size_t)r * HH + lane] = sum4(a);
  }
}

// ---------------- fused GAT layer (in-place) ---------------------------------
// Phase 0: h staged in 8-row chunks (coalesced, register-prefetched); both
//   weight sets in VGPRs; b128 LDS broadcasts. (R7, kept.)
// Phase 1: thread-per-edge logits. (R6/R7, kept.)
// Phase 2: BRANCH-FREE batch-8 gather over the padded edge list — 8 indep
//   scalar pad loads -> 8 indep p + 8 indep conflict-free x column reads ->
//   8 fma. Pads hit sentinel p_hst[ET]=0 (bitwise +0). Kills the R5-R7
//   1-deep dependent-LDS chain (~240 cyc/edge -> ~40).
__global__ __launch_bounds__(256, 2) void gat_fused5_kernel(
    float* hio,
    const int* __restrict__ csr_src, const int* __restrict__ csr_tgt,
    const int* __restrict__ plv, const int* __restrict__ pad,
    const float* __restrict__ Wl, const float* __restrict__ bl,
    const float* __restrict__ Wr, const float* __restrict__ br,
    const float* __restrict__ att, const float* __restrict__ bo) {
  __shared__ __align__(16) float xsh[2][NN * XPAD];  // 66.6 KB
  __shared__ __align__(16) float p_hst[ET + 8];      // phase0: h chunk; then p
  __shared__ int st_sh[ET];                          // src | tgt<<16
  int tid = threadIdx.x, lane = tid & 63, wid = tid >> 6;
  size_t base = (size_t)blockIdx.x * (NN * HH);

  for (int i = tid; i < ET; i += 256)
    st_sh[i] = csr_src[i] | (csr_tgt[i] << 16);

  float4 wl4[HH / 4], wr4[HH / 4];
#pragma unroll
  for (int i = 0; i < HH / 4; ++i) {
    wl4[i] = ((const float4*)(Wl + lane * HH))[i];
    wr4[i] = ((const float4*)(Wr + lane * HH))[i];
  }
  float bl_l = bl[lane], br_l = br[lane];

  // phase 0: 16 chunks x 8 rows
  float4 f4;
  if (tid < 128) f4 = *(const float4*)(hio + base + tid * 4);
#pragma unroll 1
  for (int c = 0; c < 16; ++c) {
    __syncthreads();
    if (tid < 128) *(float4*)&p_hst[tid * 4] = f4;
    if (c < 15 && tid < 128)
      f4 = *(const float4*)(hio + base + (c + 1) * 512 + tid * 4);
    __syncthreads();
    int rl = wid * 2;
#pragma unroll
    for (int rr = 0; rr < 2; ++rr) {
      const float4* hr = (const float4*)&p_hst[(rl + rr) * HH];  // broadcast
      float4 al = {bl_l, 0.f, 0.f, 0.f}, ar = {br_l, 0.f, 0.f, 0.f};
#pragma unroll
      for (int k = 0; k < HH / 4; ++k) {
        float4 hv = hr[k];
        al += hv * wl4[k];
        ar += hv * wr4[k];
      }
      int r = c * 8 + rl + rr;
      xsh[0][r * XPAD + lane] = sum4(al);
      xsh[1][r * XPAD + lane] = sum4(ar);
    }
  }
  float bo_l = bo[lane];
  __syncthreads();

  // phase 1: thread-per-edge logits + exp
#pragma unroll 1
  for (int e = tid; e < ET; e += 256) {
    int st = st_sh[e];
    int s = st & 0xffff, tg = st >> 16;
    const float* xlr = xsh[0] + s * XPAD;
    const float* xrr = xsh[1] + tg * XPAD;
    v2f a0 = {0.f, 0.f}, a1 = {0.f, 0.f};
#pragma unroll
    for (int k = 0; k < HH; k += 4) {
      v2f l0 = *(const v2f*)(xlr + k),     rr0 = *(const v2f*)(xrr + k);
      v2f l1 = *(const v2f*)(xlr + k + 2), rr1 = *(const v2f*)(xrr + k + 2);
      v2f v0 = l0 + rr0, v1 = l1 + rr1;
      v0.x = fmaxf(v0.x, 0.2f * v0.x); v0.y = fmaxf(v0.y, 0.2f * v0.y);
      v1.x = fmaxf(v1.x, 0.2f * v1.x); v1.y = fmaxf(v1.y, 0.2f * v1.y);
      v2f at0 = *(const v2f*)(att + k);
      v2f at1 = *(const v2f*)(att + k + 2);
      a0 += v0 * at0; a1 += v1 * at1;
    }
    p_hst[e] = expf((a0.x + a0.y) + (a1.x + a1.y));
  }
  if (tid == 0) p_hst[ET] = 0.f;       // pad sentinel
  __syncthreads();

  // phase 2: branch-free batch-8 gather over padded list
  int PL = plv[0];                     // uniform
#pragma unroll 1
  for (int n = wid; n < NN; n += 4) {
    const int* pl = pad + n * PL;      // per-wave uniform -> scalar loads
    float acc = 0.f, z = 0.f;
#pragma unroll 1
    for (int i = 0; i < PL; i += 8) {
      int st[8];
#pragma unroll
      for (int u = 0; u < 8; ++u) st[u] = pl[i + u];          // 8 indep s_loads
      float pv[8], xv[8];
#pragma unroll
      for (int u = 0; u < 8; ++u) {
        pv[u] = p_hst[st[u] >> 7];                            // uniform b32
        xv[u] = xsh[0][(st[u] & 127) * XPAD + lane];          // conflict-free
      }
#pragma unroll
      for (int u = 0; u < 8; ++u) { acc = fmaf(pv[u], xv[u], acc); z += pv[u]; }
    }
    hio[base + n * HH + lane] = fmaxf(acc / z + bo_l, 0.f);
  }
}

// ---------------- GRU: 3 gate waves, x prestaged, 1 barrier/step -------------
// Wave g (gate r/z/n) holds its Wih+Whh rows (128 floats/lane) in VGPRs.
// Entire sequence's x (16 KB) staged in LDS once -> no global loads in loop.
// h kept redundantly in ALL waves' lane registers (lane j = h[j]); h-dot via
// readlane (VALU pipe). Cross-wave exchange: only preactivations a_r, a_z,
// gi_n, gh_n through a 2-slot LDS ring -> exactly ONE barrier per step.
__global__ __launch_bounds__(192, 3) void gru_ws5_kernel(
    const float* __restrict__ hbuf,
    const float* __restrict__ Wih, const float* __restrict__ Whh,
    const float* __restrict__ bih, const float* __restrict__ bhh,
    const float* __restrict__ oW1, const float* __restrict__ ob1,
    const float* __restrict__ oW2, const float* __restrict__ ob2,
    const float* __restrict__ dW1, const float* __restrict__ db1,
    const float* __restrict__ dW2, const float* __restrict__ db2,
    float* __restrict__ out) {
  int lane = threadIdx.x & 63;
  int g = (int)threadIdx.x >> 6;       // 0=r, 1=z, 2=n
  int seq = blockIdx.x;                // b*N + n
  int b = seq >> 7, n = seq & (NN - 1);

  __shared__ __align__(16) float x_sh[SS][HH];   // 16 KB
  __shared__ float a_sh[2][4][HH];               // a_r, a_z, gi_n, gh_n ring

  const float* xbase = hbuf + ((size_t)(b * SS) * NN + n) * HH;
#pragma unroll 1
  for (int t = g; t < SS; t += 3)
    x_sh[t][lane] = xbase[(size_t)t * NN * HH + lane];   // coalesced 256B

  float4 wi4[HH / 4], wh4[HH / 4];     // 128 floats, register-resident
  {
    const float4* si = (const float4*)(Wih + (size_t)(g * 64 + lane) * HH);
    const float4* sh = (const float4*)(Whh + (size_t)(g * 64 + lane) * HH);
#pragma unroll
    for (int i = 0; i < HH / 4; ++i) { wi4[i] = si[i]; wh4[i] = sh[i]; }
  }
  float bi = bih[g * 64 + lane], bh = bhh[g * 64 + lane];
  float hj = 0.f;                      // h[lane], redundant in every wave
  __syncthreads();

#pragma unroll 1
  for (int t = 0; t < SS; ++t) {
    // gi: 16 uniform b128 LDS broadcasts + pk_fma
    const float4* xb = (const float4*)x_sh[t];
    float4 gi4 = {bi, 0.f, 0.f, 0.f};
#pragma unroll
    for (int k = 0; k < HH / 4; ++k) gi4 += xb[k] * wi4[k];
    // gh: readlane broadcast of own-lane h (VALU pipe, no DS)
    float g0 = bh, g1 = 0.f, g2 = 0.f, g3 = 0.f;
#pragma unroll
    for (int k = 0; k < HH; k += 4) {
      g0 = fmaf(readlane_f(hj, k),     wh4[k / 4].x, g0);
      g1 = fmaf(readlane_f(hj, k + 1), wh4[k / 4].y, g1);
      g2 = fmaf(readlane_f(hj, k + 2), wh4[k / 4].z, g2);
      g3 = fmaf(readlane_f(hj, k + 3), wh4[k / 4].w, g3);
    }
    float gi = sum4(gi4);
    float gh = (g0 + g1) + (g2 + g3);
    int sl = t & 1;
    if (g == 2) { a_sh[sl][2][lane] = gi; a_sh[sl][3][lane] = gh; }
    else        { a_sh[sl][g][lane] = gi + gh; }
    __syncthreads();                   // the ONLY barrier per step
    float rr = sigmoidf_(a_sh[sl][0][lane]);
    float zz = sigmoidf_(a_sh[sl][1][lane]);
    float nn2 = tanhf(a_sh[sl][2][lane] + rr * a_sh[sl][3][lane]);
    hj = (1.f - zz) * nn2 + zz * hj;   // identical in all waves (same ops)
  }

  // fused heads on wave 0: lanes 0-31 order head, 32-63 demand head
  if (g == 0) {
    int hf = lane >> 5, jp = lane & 31;
    const float* W1 = hf ? dW1 : oW1;
    const float* b1 = hf ? db1 : ob1;
    const float* W2 = hf ? dW2 : oW2;
    const float* b2 = hf ? db2 : ob2;
    float4 wv[HH / 4];
#pragma unroll
    for (int i = 0; i < HH / 4; ++i) wv[i] = ((const float4*)(W1 + jp * HH))[i];
    float acc = b1[jp];
#pragma unroll
    for (int k = 0; k < HH; k += 4) {
      acc = fmaf(readlane_f(hj, k),     wv[k / 4].x, acc);
      acc = fmaf(readlane_f(hj, k + 1), wv[k / 4].y, acc);
      acc = fmaf(readlane_f(hj, k + 2), wv[k / 4].z, acc);
      acc = fmaf(readlane_f(hj, k + 3), wv[k / 4].w, acc);
    }
    float val = fmaxf(acc, 0.f) * W2[jp];
    val += __shfl_down(val, 16, 32);
    val += __shfl_down(val, 8, 32);
    val += __shfl_down(val, 4, 32);
    val += __shfl_down(val, 2, 32);
    val += __shfl_down(val, 1, 32);
    if (jp == 0) out[hf * (BB * NN) + seq] = val + b2[0];
  }
}

// ---------------- launch -----------------------------------------------------
extern "C" void kernel_launch(void* const* d_in, const int* in_sizes, int n_in,
                              void* d_out, int out_size, void* d_ws, size_t ws_size,
                              hipStream_t stream) {
  const float* x       = (const float*)d_in[0];
  const int*   ei      = (const int*)d_in[1];
  const float* in_W    = (const float*)d_in[2];
  const float* in_b    = (const float*)d_in[3];
  const float* gat_Wl  = (const float*)d_in[4];
  const float* gat_bl  = (const float*)d_in[5];
  const float* gat_Wr  = (const float*)d_in[6];
  const float* gat_br  = (const float*)d_in[7];
  const float* gat_att = (const float*)d_in[8];
  const float* gat_bias= (const float*)d_in[9];
  const float* gru_Wih = (const float*)d_in[10];
  const float* gru_Whh = (const float*)d_in[11];
  const float* gru_bih = (const float*)d_in[12];
  const float* gru_bhh = (const float*)d_in[13];
  const float* oh_W1   = (const float*)d_in[14];
  const float* oh_b1   = (const float*)d_in[15];
  const float* oh_W2   = (const float*)d_in[16];
  const float* oh_b2   = (const float*)d_in[17];
  const float* dh_W1   = (const float*)d_in[18];
  const float* dh_b1   = (const float*)d_in[19];
  const float* dh_W2   = (const float*)d_in[20];
  const float* dh_b2   = (const float*)d_in[21];
  float* out = (float*)d_out;

  char* ws = (char*)d_ws;
  size_t hbytes = (size_t)BB * SS * NN * HH * sizeof(float);   // 33.5 MB
  float* hbuf = (float*)ws;
  int* csr_src = (int*)(ws + hbytes);
  int* csr_tgt = csr_src + ET;
  int* plv     = csr_tgt + ET;
  int* pad     = plv + 8;              // up to NN*1160 ints (~0.6 MB)

  setup_csr_kernel<<<1, 256, 0, stream>>>(ei, csr_src, csr_tgt, plv, pad);
  input_proj2_kernel<<<(BB * SS * NN) / 128, 256, 0, stream>>>(x, in_W, in_b, hbuf);
  gat_fused5_kernel<<<BB * SS, 256, 0, stream>>>(
      hbuf, csr_src, csr_tgt, plv, pad,
      gat_Wl, gat_bl, gat_Wr, gat_br, gat_att, gat_bias);
  gat_fused5_kernel<<<BB * SS, 256, 0, stream>>>(
      hbuf, csr_src, csr_tgt, plv, pad,
      gat_Wl + HH * HH, gat_bl + HH, gat_Wr + HH * HH, gat_br + HH,
      gat_att + HH, gat_bias + HH);
  gru_ws5_kernel<<<BB * NN, 192, 0, stream>>>(
      hbuf, gru_Wih, gru_Whh, gru_bih, gru_bhh,
      oh_W1, oh_b1, oh_W2, oh_b2, dh_W1, dh_b1, dh_W2, dh_b2, out);
}